// Round 6
// baseline (155.510 us; speedup 1.0000x reference)
//
#include <hip/hip_runtime.h>
#include <stdint.h>

typedef __bf16 bf16;
typedef __bf16 bf16x8 __attribute__((ext_vector_type(8)));
typedef __bf16 bf16x4 __attribute__((ext_vector_type(4)));
typedef float f32x4 __attribute__((ext_vector_type(4)));

#define MFMA16x16x32(A, B, C) __builtin_amdgcn_mfma_f32_16x16x32_bf16((A), (B), (C), 0, 0, 0)

__device__ __forceinline__ void gload_lds16(const void* g, void* l) {
  __builtin_amdgcn_global_load_lds((const __attribute__((address_space(1))) void*)g,
                                   (__attribute__((address_space(3))) void*)l,
                                   16, 0, 0);
}

__device__ __forceinline__ float fexp2(float x) { return __builtin_amdgcn_exp2f(x); }

__device__ __forceinline__ bf16x8 cvt8(float4 a, float4 b) {
  bf16x8 o;
  o[0] = (bf16)a.x; o[1] = (bf16)a.y; o[2] = (bf16)a.z; o[3] = (bf16)a.w;
  o[4] = (bf16)b.x; o[5] = (bf16)b.y; o[6] = (bf16)b.z; o[7] = (bf16)b.w;
  return o;
}

// ---------------- projection GEMM: C = A[M,512] @ B[N,512]^T ----------------
// 128x64 tile, BK=32, single barrier/iter, f32 inputs cast during reg-staging.
// MODE 0: Q  — A=x1 f32, B=Wq f32, out bf16 [b][h][s][d] * scale
// MODE 1: KV — A=x2 f32, bn<8: B=Wk -> K [b][h][s][d]; bn>=8: B=Wv -> V^T [b][h][d][s]
// MODE 2: out — A=AO bf16 (glds staging), B=Wo f32, out f32 [M,512] + bias
template <int MODE>
__global__ __launch_bounds__(256, 2) void proj_kernel(
    const void* __restrict__ Aptr, const float* __restrict__ B0f,
    const float* __restrict__ B1f, void* __restrict__ C0,
    void* __restrict__ C1, const float* __restrict__ bias, float scale) {
  __shared__ bf16 As[2][128 * 32];
  __shared__ bf16 Bs[2][64 * 32];
  const int tid = threadIdx.x;
  const int w = tid >> 6, l = tid & 63;
  const int wr = w >> 1, wc = w & 1;
  const int lr = l & 15, lg = l >> 4;
  const int bm = blockIdx.x, bn = blockIdx.y;
  const int K = 512;

  const float* Bf = (MODE == 1 && bn >= 8) ? B1f + (size_t)(bn - 8) * 64 * K
                                           : B0f + (size_t)bn * 64 * K;
  const float* Af32 = (const float*)Aptr;
  const bf16* Abf = (const bf16*)Aptr;

  // chunk = 16 rows x 32 elems; lane: row=l>>2, slot=l&3; XOR swizzle on col
  const int c_row = l >> 2;
  const int c_s = l & 3;
  const int sw = (c_s ^ (c_row & 3)) * 8;  // swizzled phys col (also glds source col)

  float4 la[2][2], lb[2];

  auto issue = [&](int t, int bb) {
    const int k0 = t * 32;
    if constexpr (MODE == 2) {
#pragma unroll
      for (int i = 0; i < 2; i++) {
        const int q = w + i * 4;
        gload_lds16(Abf + (size_t)(bm * 128 + q * 16 + c_row) * K + k0 + sw, &As[bb][q * 512]);
      }
    } else {
#pragma unroll
      for (int i = 0; i < 2; i++) {
        const int q = w + i * 4;
        const float* p = Af32 + (size_t)(bm * 128 + q * 16 + c_row) * K + k0 + c_s * 8;
        la[i][0] = *reinterpret_cast<const float4*>(p);
        la[i][1] = *reinterpret_cast<const float4*>(p + 4);
      }
    }
    const float* pb = Bf + (size_t)(w * 16 + c_row) * K + k0 + c_s * 8;
    lb[0] = *reinterpret_cast<const float4*>(pb);
    lb[1] = *reinterpret_cast<const float4*>(pb + 4);
  };
  auto commit = [&](int bb) {
    if constexpr (MODE != 2) {
#pragma unroll
      for (int i = 0; i < 2; i++) {
        const int q = w + i * 4;
        *reinterpret_cast<bf16x8*>(&As[bb][q * 512 + c_row * 32 + sw]) = cvt8(la[i][0], la[i][1]);
      }
    }
    *reinterpret_cast<bf16x8*>(&Bs[bb][w * 512 + c_row * 32 + sw]) = cvt8(lb[0], lb[1]);
  };

  f32x4 acc[4][2] = {};
  const int swz = (lr & 3) * 8;  // read-side swizzle

  issue(0, 0);
  asm volatile("s_waitcnt vmcnt(0)" ::: "memory");
  commit(0);
  __syncthreads();

  int cur = 0;
  const int NT = K / 32;  // 16
  for (int t = 0; t < NT; t++) {
    if (t + 1 < NT) issue(t + 1, cur ^ 1);
    bf16x8 a[4], b[2];
#pragma unroll
    for (int mi = 0; mi < 4; mi++)
      a[mi] = *reinterpret_cast<const bf16x8*>(
          &As[cur][(wr * 64 + mi * 16 + lr) * 32 + (lg * 8 ^ swz)]);
#pragma unroll
    for (int ni = 0; ni < 2; ni++)
      b[ni] = *reinterpret_cast<const bf16x8*>(
          &Bs[cur][(wc * 32 + ni * 16 + lr) * 32 + (lg * 8 ^ swz)]);
#pragma unroll
    for (int mi = 0; mi < 4; mi++)
#pragma unroll
      for (int ni = 0; ni < 2; ni++)
        acc[mi][ni] = MFMA16x16x32(a[mi], b[ni], acc[mi][ni]);
    if (t + 1 < NT) {
      asm volatile("s_waitcnt vmcnt(0)" ::: "memory");
      commit(cur ^ 1);
    }
    __syncthreads();
    cur ^= 1;
  }

  // epilogue: C/D layout col=lane&15, row=(lane>>4)*4+reg
#pragma unroll
  for (int mi = 0; mi < 4; mi++) {
    const int m0 = bm * 128 + wr * 64 + mi * 16 + lg * 4;
#pragma unroll
    for (int ni = 0; ni < 2; ni++) {
      const int n = wc * 32 + ni * 16 + lr;  // 0..63 within tile
      if constexpr (MODE == 0) {
#pragma unroll
        for (int r = 0; r < 4; r++) {
          const int m = m0 + r, gn = bn * 64 + n;
          float v = acc[mi][ni][r] * scale;
          size_t d = (size_t)((m >> 11) * 8 + (gn >> 6)) * 131072 + (size_t)(m & 2047) * 64 + (gn & 63);
          ((bf16*)C0)[d] = (bf16)v;
        }
      } else if constexpr (MODE == 1) {
        if (bn < 8) {
#pragma unroll
          for (int r = 0; r < 4; r++) {
            const int m = m0 + r, gn = bn * 64 + n;
            size_t d = (size_t)((m >> 11) * 8 + (gn >> 6)) * 131072 + (size_t)(m & 2047) * 64 + (gn & 63);
            ((bf16*)C0)[d] = (bf16)acc[mi][ni][r];
          }
        } else {
          const int nv = (bn - 8) * 64 + n;  // h*64+d
          bf16x4 pv;
#pragma unroll
          for (int r = 0; r < 4; r++) pv[r] = (bf16)acc[mi][ni][r];
          size_t base = ((size_t)(m0 >> 11) * 512 + nv) * 2048 + (m0 & 2047);
          *reinterpret_cast<bf16x4*>((bf16*)C1 + base) = pv;
        }
      } else {
        const int gn = bn * 64 + n;
        const float bv = bias[gn];
#pragma unroll
        for (int r = 0; r < 4; r++)
          ((float*)C0)[(size_t)(m0 + r) * 512 + gn] = acc[mi][ni][r] + bv;
      }
    }
  }
}

// ---------------- flash attention (swapped-QK, fixed-max exp2, 8 waves) ----------------
// Q: [BH][2048][64] (pre-scaled by 0.125*log2e), K: [BH][2048][64], V^T: [BH][64][2048]
// Block: 512 thr (8 waves = 2/SIMD), 256 q-rows (32/wave), KV tiles of 64, grid 256.
// Single barrier per iter: stage(t+1) -> compute(t) -> vmcnt(0) -> barrier.
__global__ __launch_bounds__(512, 1) void attn_kernel(
    const bf16* __restrict__ Q, const bf16* __restrict__ Kk,
    const bf16* __restrict__ Vt, bf16* __restrict__ AO) {
  __shared__ bf16 Kb2[2][64 * 64];
  __shared__ bf16 Vb2[2][64 * 64];
  __shared__ bf16 Ps[8][32 * 64];  // per-wave [32 q][64 kv]

  const int tid = threadIdx.x;
  const int w = tid >> 6, l = tid & 63;  // w 0..7
  const int lr = l & 15, lg = l >> 4;

  // XCD-aware decode: grid 256, lin&7 = XCD; 4 bh per XCD -> K/V L2-resident (2MB/XCD)
  const int lin = blockIdx.x;  // 0..255
  const int xcd = lin & 7;
  const int m = lin >> 3;      // 0..31
  const int bh = xcd * 4 + (m & 3);
  const int qb = m >> 2;       // 0..7
  const int b = bh >> 3, h = bh & 7;

  const bf16* Qb = Q + (size_t)bh * 131072;
  const bf16* Kb = Kk + (size_t)bh * 131072;
  const bf16* Vb = Vt + (size_t)bh * 131072;

  const int q0 = qb * 256 + w * 32;

  // Q fragments (B-operand): qf[i]: col q = i*16+lr, k = d = ks*32+lg*8+j
  bf16x8 qf[2][2];
#pragma unroll
  for (int i = 0; i < 2; i++)
#pragma unroll
    for (int ks = 0; ks < 2; ks++)
      qf[i][ks] = *reinterpret_cast<const bf16x8*>(
          Qb + (size_t)(q0 + i * 16 + lr) * 64 + ks * 32 + lg * 8);

  // staging: chunk = 8 rows x 64 elems = 1KB; wave w stages chunk w of K and of V.
  const int crow = l >> 3;
  const int scol = ((l & 7) ^ crow) * 8;

  auto stage = [&](int kv0, int bb) {
    const int row = w * 8 + crow;
    gload_lds16(Kb + (size_t)(kv0 + row) * 64 + scol, &Kb2[bb][w * 512]);
    gload_lds16(Vb + (size_t)row * 2048 + kv0 + scol, &Vb2[bb][w * 512]);
  };

  f32x4 oacc[2][4] = {};
  float lsum[2] = {0.f, 0.f};
  const int sw8 = (lr & 7) * 8;

  stage(0, 0);
  asm volatile("s_waitcnt vmcnt(0)" ::: "memory");
  __syncthreads();

  for (int t = 0; t < 32; t++) {
    const int cur = t & 1;
    if (t < 31) stage((t + 1) * 64, cur ^ 1);

    // K fragments (shared across q-frags)
    bf16x8 kb[2][4];
#pragma unroll
    for (int ks = 0; ks < 2; ks++)
#pragma unroll
      for (int c = 0; c < 4; c++)
        kb[ks][c] = *reinterpret_cast<const bf16x8*>(
            &Kb2[cur][(c * 16 + lr) * 64 + ((ks * 32 + lg * 8) ^ sw8)]);

    // S^T = K Q^T per q-frag; exp2; stash P
#pragma unroll
    for (int i = 0; i < 2; i++) {
      f32x4 st[4] = {};
#pragma unroll
      for (int ks = 0; ks < 2; ks++)
#pragma unroll
        for (int c = 0; c < 4; c++)
          st[c] = MFMA16x16x32(kb[ks][c], qf[i][ks], st[c]);
#pragma unroll
      for (int c = 0; c < 4; c++) {
        float e0 = fexp2(st[c][0]);
        float e1 = fexp2(st[c][1]);
        float e2 = fexp2(st[c][2]);
        float e3 = fexp2(st[c][3]);
        lsum[i] += (e0 + e1) + (e2 + e3);
        bf16x4 pk;
        pk[0] = (bf16)e0; pk[1] = (bf16)e1; pk[2] = (bf16)e2; pk[3] = (bf16)e3;
        *reinterpret_cast<bf16x4*>(
            &Ps[w][(i * 16 + lr) * 64 + ((c * 16 + lg * 4) ^ sw8)]) = pk;
      }
    }

    // V fragments (shared across q-frags)
    bf16x8 vb[2][4];
#pragma unroll
    for (int ks = 0; ks < 2; ks++)
#pragma unroll
      for (int c = 0; c < 4; c++)
        vb[ks][c] = *reinterpret_cast<const bf16x8*>(
            &Vb2[cur][(c * 16 + lr) * 64 + ((ks * 32 + lg * 8) ^ sw8)]);

    // O += P @ V
#pragma unroll
    for (int i = 0; i < 2; i++)
#pragma unroll
      for (int ks = 0; ks < 2; ks++) {
        bf16x8 pa = *reinterpret_cast<const bf16x8*>(
            &Ps[w][(i * 16 + lr) * 64 + ((ks * 32 + lg * 8) ^ sw8)]);
#pragma unroll
        for (int c = 0; c < 4; c++)
          oacc[i][c] = MFMA16x16x32(pa, vb[ks][c], oacc[i][c]);
      }

    if (t < 31) asm volatile("s_waitcnt vmcnt(0)" ::: "memory");
    __syncthreads();
  }

  // row-sum reduce: lanes lr, lr+16, lr+32, lr+48 hold partials of q-row i*16+lr
#pragma unroll
  for (int i = 0; i < 2; i++) {
    lsum[i] += __shfl_xor(lsum[i], 16);
    lsum[i] += __shfl_xor(lsum[i], 32);
  }

  // normalize + write AO[b*2048+q][h*64+d]; oacc row q = i*16 + lg*4 + r
#pragma unroll
  for (int i = 0; i < 2; i++) {
#pragma unroll
    for (int r = 0; r < 4; r++) {
      const float inv = 1.f / __shfl(lsum[i], lg * 4 + r);
      const int qrow = q0 + i * 16 + lg * 4 + r;
#pragma unroll
      for (int c = 0; c < 4; c++)
        AO[(size_t)(b * 2048 + qrow) * 512 + h * 64 + c * 16 + lr] = (bf16)(oacc[i][c][r] * inv);
    }
  }
}

// ---------------- launch ----------------
extern "C" void kernel_launch(void* const* d_in, const int* in_sizes, int n_in,
                              void* d_out, int out_size, void* d_ws, size_t ws_size,
                              hipStream_t stream) {
  (void)in_sizes; (void)n_in; (void)out_size; (void)ws_size;
  const float* x1 = (const float*)d_in[0];
  const float* x2 = (const float*)d_in[1];
  const float* Wq = (const float*)d_in[2];
  const float* Wk = (const float*)d_in[3];
  const float* Wv = (const float*)d_in[4];
  const float* Wo = (const float*)d_in[5];
  const float* bo = (const float*)d_in[6];

  uint8_t* ws = (uint8_t*)d_ws;
  bf16* Qws = (bf16*)(ws + 0);          // [b][h][s][64]  8,388,608 B
  bf16* Kws = (bf16*)(ws + 8388608);    // [b][h][s][64]
  bf16* Vtw = (bf16*)(ws + 16777216);   // [b][h][64][s]
  bf16* AO  = (bf16*)(ws + 25165824);   // [8192][512]

  // Q = (x1 Wq^T) * 0.125*log2e   (cast fused into staging)
  proj_kernel<0><<<dim3(64, 8), 256, 0, stream>>>(x1, Wq, nullptr, Qws, nullptr, nullptr, 0.18033688011112f);
  // K = x2 Wk^T ; V^T = (x2 Wv^T)^T  (fused, x2 read once)
  proj_kernel<1><<<dim3(64, 16), 256, 0, stream>>>(x2, Wk, Wv, Kws, Vtw, nullptr, 1.0f);

  attn_kernel<<<256, 512, 0, stream>>>(Qws, Kws, Vtw, AO);

  // out = AO @ Wo^T + bo  (f32)
  proj_kernel<2><<<dim3(64, 8), 256, 0, stream>>>(AO, Wo, nullptr, d_out, nullptr, bo, 1.0f);
}

// Round 7
// 102.750 us; speedup vs baseline: 1.5135x; 1.5135x over previous
//
#include <hip/hip_runtime.h>
#include <stdint.h>

typedef __bf16 bf16;
typedef __bf16 bf16x8 __attribute__((ext_vector_type(8)));
typedef __bf16 bf16x4 __attribute__((ext_vector_type(4)));
typedef float f32x4 __attribute__((ext_vector_type(4)));

#define MFMA16x16x32(A, B, C) __builtin_amdgcn_mfma_f32_16x16x32_bf16((A), (B), (C), 0, 0, 0)

__device__ __forceinline__ void gload_lds16(const void* g, void* l) {
  __builtin_amdgcn_global_load_lds((const __attribute__((address_space(1))) void*)g,
                                   (__attribute__((address_space(3))) void*)l,
                                   16, 0, 0);
}

__device__ __forceinline__ float fexp2(float x) { return __builtin_amdgcn_exp2f(x); }

__device__ __forceinline__ bf16x8 cvt8(float4 a, float4 b) {
  bf16x8 o;
  o[0] = (bf16)a.x; o[1] = (bf16)a.y; o[2] = (bf16)a.z; o[3] = (bf16)a.w;
  o[4] = (bf16)b.x; o[5] = (bf16)b.y; o[6] = (bf16)b.z; o[7] = (bf16)b.w;
  return o;
}

// ---------------- x1+x2 -> bf16 (contiguous dst) ----------------
__global__ void cast_x(const float* __restrict__ x1, const float* __restrict__ x2,
                       bf16* __restrict__ out) {
  const size_t i = ((size_t)blockIdx.x * blockDim.x + threadIdx.x) * 8;
  const float* src = (i < 4194304) ? x1 + i : x2 + (i - 4194304);
  float4 a = *reinterpret_cast<const float4*>(src);
  float4 b = *reinterpret_cast<const float4*>(src + 4);
  *reinterpret_cast<bf16x8*>(out + i) = cvt8(a, b);
}

// ---------------- projection GEMM: C = A[M,512] @ W[N,512]^T ----------------
// 128x64 tile, BK=32. A: bf16 via global_load_lds, 2 tiles in flight, counted vmcnt.
// W: f32, reg-staged 2-deep with fused cast. Single barrier per iteration.
// MODE 0 (QKV fused): bn<8 -> Q=x1@Wq^T *scale -> [b][h][s][d]; bn<16 -> K=x2@Wk^T;
//                     else V^T=(x2@Wv^T)^T -> [b][h][d][s]
// MODE 1 (out): A=AO bf16, W=Wo, out f32 [M,512] + bias
template <int MODE>
__global__ __launch_bounds__(256, 4) void proj_kernel(
    const bf16* __restrict__ A0, const bf16* __restrict__ A1,
    const float* __restrict__ W0, const float* __restrict__ W1,
    const float* __restrict__ W2, void* __restrict__ C0, void* __restrict__ C1,
    void* __restrict__ C2, const float* __restrict__ bias) {
  __shared__ bf16 As[2][128 * 32];
  __shared__ bf16 Bs[2][64 * 32];
  const int tid = threadIdx.x;
  const int w = tid >> 6, l = tid & 63;
  const int wr = w >> 1, wc = w & 1;
  const int lr = l & 15, lg = l >> 4;
  const int bm = blockIdx.x, bn = blockIdx.y;
  const int K = 512;

  int sel = 0, wn = bn;
  const bf16* A;
  const float* Bf;
  if constexpr (MODE == 0) {
    sel = bn >> 3;
    wn = bn & 7;
    A = (sel == 0) ? A0 : A1;
    Bf = ((sel == 0) ? W0 : (sel == 1) ? W1 : W2) + (size_t)wn * 64 * K;
  } else {
    A = A0;
    Bf = W0 + (size_t)bn * 64 * K;
  }

  // chunk = 16 rows x 32 elems; lane: row=l>>2, slot=l&3; XOR swizzle on col
  const int c_row = l >> 2;
  const int c_s = l & 3;
  const int sw = (c_s ^ (c_row & 3)) * 8;  // pre-swizzled source/phys col

  float4 lb[2][2];
  auto issue_B = [&](int t, int s) {
    const float* pb = Bf + (size_t)(w * 16 + c_row) * K + t * 32 + c_s * 8;
    lb[s][0] = *reinterpret_cast<const float4*>(pb);
    lb[s][1] = *reinterpret_cast<const float4*>(pb + 4);
  };
  auto commit_B = [&](int s, int bb) {
    *reinterpret_cast<bf16x8*>(&Bs[bb][w * 512 + c_row * 32 + sw]) = cvt8(lb[s][0], lb[s][1]);
  };
  auto issue_A = [&](int t, int bb) {
#pragma unroll
    for (int i = 0; i < 2; i++) {
      const int q = w + i * 4;
      gload_lds16(A + (size_t)(bm * 128 + q * 16 + c_row) * K + t * 32 + sw, &As[bb][q * 512]);
    }
  };

  f32x4 acc[4][2] = {};
  const int swz = (lr & 3) * 8;  // read-side swizzle

  // prologue: 2 tiles in flight
  issue_B(0, 0);
  issue_A(0, 0);
  issue_B(1, 1);
  issue_A(1, 1);
  asm volatile("s_waitcnt vmcnt(4)" ::: "memory");  // tile0 A+B done
  commit_B(0, 0);
  __syncthreads();

  const int NT = K / 32;  // 16
  for (int t = 0; t < NT; t++) {
    const int cur = t & 1;
    if (t + 2 < NT) issue_B(t + 2, cur);  // set[t&1] free (tile t committed)

    bf16x8 a[4], b[2];
#pragma unroll
    for (int mi = 0; mi < 4; mi++)
      a[mi] = *reinterpret_cast<const bf16x8*>(
          &As[cur][(wr * 64 + mi * 16 + lr) * 32 + (lg * 8 ^ swz)]);
#pragma unroll
    for (int ni = 0; ni < 2; ni++)
      b[ni] = *reinterpret_cast<const bf16x8*>(
          &Bs[cur][(wc * 32 + ni * 16 + lr) * 32 + (lg * 8 ^ swz)]);
#pragma unroll
    for (int mi = 0; mi < 4; mi++)
#pragma unroll
      for (int ni = 0; ni < 2; ni++)
        acc[mi][ni] = MFMA16x16x32(a[mi], b[ni], acc[mi][ni]);

    if (t + 1 < NT) {
      if (t + 2 < NT) asm volatile("s_waitcnt vmcnt(2)" ::: "memory");  // t+1 A,B done
      else            asm volatile("s_waitcnt vmcnt(0)" ::: "memory");
      commit_B((t + 1) & 1, cur ^ 1);
      __syncthreads();
      if (t + 2 < NT) issue_A(t + 2, cur);  // all waves done reading As[cur]
    }
  }

  // epilogue: C/D layout col=lane&15, row=(lane>>4)*4+reg
#pragma unroll
  for (int mi = 0; mi < 4; mi++) {
    const int m0 = bm * 128 + wr * 64 + mi * 16 + lg * 4;
#pragma unroll
    for (int ni = 0; ni < 2; ni++) {
      const int n = wc * 32 + ni * 16 + lr;  // 0..63 in tile
      if constexpr (MODE == 0) {
        const int gn = wn * 64 + n;  // h*64+d
        if (sel < 2) {
          bf16* dst = (bf16*)((sel == 0) ? C0 : C1);
          const float scale = (sel == 0) ? 0.18033688011112f : 1.0f;
#pragma unroll
          for (int r = 0; r < 4; r++) {
            const int m = m0 + r;
            size_t d = (size_t)((m >> 11) * 8 + (gn >> 6)) * 131072 + (size_t)(m & 2047) * 64 + (gn & 63);
            dst[d] = (bf16)(acc[mi][ni][r] * scale);
          }
        } else {
          bf16x4 pv;
#pragma unroll
          for (int r = 0; r < 4; r++) pv[r] = (bf16)acc[mi][ni][r];
          size_t base = ((size_t)(m0 >> 11) * 512 + gn) * 2048 + (m0 & 2047);
          *reinterpret_cast<bf16x4*>((bf16*)C2 + base) = pv;
        }
      } else {
        const int gn = bn * 64 + n;
        const float bv = bias[gn];
#pragma unroll
        for (int r = 0; r < 4; r++)
          ((float*)C0)[(size_t)(m0 + r) * 512 + gn] = acc[mi][ni][r] + bv;
      }
    }
  }
}

// ---------------- flash attention (swapped-QK, fixed-max exp2, 8 waves) ----------------
// Q: [BH][2048][64] (pre-scaled by 0.125*log2e), K: [BH][2048][64], V^T: [BH][64][2048]
// Block: 512 thr (8 waves = 2/SIMD), 256 q-rows (32/wave), KV tiles of 64, grid 256.
__global__ __launch_bounds__(512, 1) void attn_kernel(
    const bf16* __restrict__ Q, const bf16* __restrict__ Kk,
    const bf16* __restrict__ Vt, bf16* __restrict__ AO) {
  __shared__ bf16 Kb2[2][64 * 64];
  __shared__ bf16 Vb2[2][64 * 64];
  __shared__ bf16 Ps[8][32 * 64];  // per-wave [32 q][64 kv]

  const int tid = threadIdx.x;
  const int w = tid >> 6, l = tid & 63;  // w 0..7
  const int lr = l & 15, lg = l >> 4;

  // XCD-aware decode: grid 256, lin&7 = XCD; 4 bh per XCD -> K/V L2-resident (2MB/XCD)
  const int lin = blockIdx.x;  // 0..255
  const int xcd = lin & 7;
  const int m = lin >> 3;      // 0..31
  const int bh = xcd * 4 + (m & 3);
  const int qb = m >> 2;       // 0..7
  const int b = bh >> 3, h = bh & 7;

  const bf16* Qb = Q + (size_t)bh * 131072;
  const bf16* Kb = Kk + (size_t)bh * 131072;
  const bf16* Vb = Vt + (size_t)bh * 131072;

  const int q0 = qb * 256 + w * 32;

  // Q fragments (B-operand): qf[i]: col q = i*16+lr, k = d = ks*32+lg*8+j
  bf16x8 qf[2][2];
#pragma unroll
  for (int i = 0; i < 2; i++)
#pragma unroll
    for (int ks = 0; ks < 2; ks++)
      qf[i][ks] = *reinterpret_cast<const bf16x8*>(
          Qb + (size_t)(q0 + i * 16 + lr) * 64 + ks * 32 + lg * 8);

  // staging: chunk = 8 rows x 64 elems = 1KB; wave w stages chunk w of K and of V.
  const int crow = l >> 3;
  const int scol = ((l & 7) ^ crow) * 8;

  auto stage = [&](int kv0, int bb) {
    const int row = w * 8 + crow;
    gload_lds16(Kb + (size_t)(kv0 + row) * 64 + scol, &Kb2[bb][w * 512]);
    gload_lds16(Vb + (size_t)row * 2048 + kv0 + scol, &Vb2[bb][w * 512]);
  };

  f32x4 oacc[2][4] = {};
  float lsum[2] = {0.f, 0.f};
  const int sw8 = (lr & 7) * 8;

  stage(0, 0);
  asm volatile("s_waitcnt vmcnt(0)" ::: "memory");
  __syncthreads();

  for (int t = 0; t < 32; t++) {
    const int cur = t & 1;
    if (t < 31) stage((t + 1) * 64, cur ^ 1);

    // K fragments (shared across q-frags)
    bf16x8 kb[2][4];
#pragma unroll
    for (int ks = 0; ks < 2; ks++)
#pragma unroll
      for (int c = 0; c < 4; c++)
        kb[ks][c] = *reinterpret_cast<const bf16x8*>(
            &Kb2[cur][(c * 16 + lr) * 64 + ((ks * 32 + lg * 8) ^ sw8)]);

    // S^T = K Q^T per q-frag; exp2; stash P
#pragma unroll
    for (int i = 0; i < 2; i++) {
      f32x4 st[4] = {};
#pragma unroll
      for (int ks = 0; ks < 2; ks++)
#pragma unroll
        for (int c = 0; c < 4; c++)
          st[c] = MFMA16x16x32(kb[ks][c], qf[i][ks], st[c]);
#pragma unroll
      for (int c = 0; c < 4; c++) {
        float e0 = fexp2(st[c][0]);
        float e1 = fexp2(st[c][1]);
        float e2 = fexp2(st[c][2]);
        float e3 = fexp2(st[c][3]);
        lsum[i] += (e0 + e1) + (e2 + e3);
        bf16x4 pk;
        pk[0] = (bf16)e0; pk[1] = (bf16)e1; pk[2] = (bf16)e2; pk[3] = (bf16)e3;
        *reinterpret_cast<bf16x4*>(
            &Ps[w][(i * 16 + lr) * 64 + ((c * 16 + lg * 4) ^ sw8)]) = pk;
      }
    }

    // V fragments (shared across q-frags)
    bf16x8 vb[2][4];
#pragma unroll
    for (int ks = 0; ks < 2; ks++)
#pragma unroll
      for (int c = 0; c < 4; c++)
        vb[ks][c] = *reinterpret_cast<const bf16x8*>(
            &Vb2[cur][(c * 16 + lr) * 64 + ((ks * 32 + lg * 8) ^ sw8)]);

    // O += P @ V
#pragma unroll
    for (int i = 0; i < 2; i++)
#pragma unroll
      for (int ks = 0; ks < 2; ks++) {
        bf16x8 pa = *reinterpret_cast<const bf16x8*>(
            &Ps[w][(i * 16 + lr) * 64 + ((ks * 32 + lg * 8) ^ sw8)]);
#pragma unroll
        for (int c = 0; c < 4; c++)
          oacc[i][c] = MFMA16x16x32(pa, vb[ks][c], oacc[i][c]);
      }

    if (t < 31) asm volatile("s_waitcnt vmcnt(0)" ::: "memory");
    __syncthreads();
  }

  // row-sum reduce: lanes lr, lr+16, lr+32, lr+48 hold partials of q-row i*16+lr
#pragma unroll
  for (int i = 0; i < 2; i++) {
    lsum[i] += __shfl_xor(lsum[i], 16);
    lsum[i] += __shfl_xor(lsum[i], 32);
  }

  // normalize + write AO[b*2048+q][h*64+d]; oacc row q = i*16 + lg*4 + r
#pragma unroll
  for (int i = 0; i < 2; i++) {
#pragma unroll
    for (int r = 0; r < 4; r++) {
      const float inv = 1.f / __shfl(lsum[i], lg * 4 + r);
      const int qrow = q0 + i * 16 + lg * 4 + r;
#pragma unroll
      for (int c = 0; c < 4; c++)
        AO[(size_t)(b * 2048 + qrow) * 512 + h * 64 + c * 16 + lr] = (bf16)(oacc[i][c][r] * inv);
    }
  }
}

// ---------------- launch ----------------
extern "C" void kernel_launch(void* const* d_in, const int* in_sizes, int n_in,
                              void* d_out, int out_size, void* d_ws, size_t ws_size,
                              hipStream_t stream) {
  (void)in_sizes; (void)n_in; (void)out_size; (void)ws_size;
  const float* x1 = (const float*)d_in[0];
  const float* x2 = (const float*)d_in[1];
  const float* Wq = (const float*)d_in[2];
  const float* Wk = (const float*)d_in[3];
  const float* Wv = (const float*)d_in[4];
  const float* Wo = (const float*)d_in[5];
  const float* bo = (const float*)d_in[6];

  uint8_t* ws = (uint8_t*)d_ws;
  bf16* x1b = (bf16*)(ws + 0);          // 8,388,608 B (x1b + x2b contiguous)
  bf16* x2b = (bf16*)(ws + 8388608);
  bf16* AO  = (bf16*)(ws + 0);          // aliases x1b/x2b (dead after qkv_proj)
  bf16* Qws = (bf16*)(ws + 16777216);   // [b][h][s][64]
  bf16* Kws = (bf16*)(ws + 25165824);   // [b][h][s][64]
  bf16* Vtw = (bf16*)(ws + 33554432);   // [b][h][64][s]  (total 41.9 MB)

  // cast x1+x2 -> bf16 (one launch)
  cast_x<<<4096, 256, 0, stream>>>(x1, x2, x1b);

  // Q|K|V fused projection: bn<8 Q (x1,*0.125*log2e), bn<16 K, else V^T
  proj_kernel<0><<<dim3(64, 24), 256, 0, stream>>>(x1b, x2b, Wq, Wk, Wv, Qws, Kws, Vtw, nullptr);

  attn_kernel<<<256, 512, 0, stream>>>(Qws, Kws, Vtw, AO);

  // out = AO @ Wo^T + bo (f32)
  proj_kernel<1><<<dim3(64, 8), 256, 0, stream>>>(AO, nullptr, Wo, nullptr, nullptr, d_out, nullptr, nullptr, bo);
}